// Round 1
// baseline (965.249 us; speedup 1.0000x reference)
//
#include <hip/hip_runtime.h>
#include <cstddef>
#include <cstdint>

#define N_NODES 100000
#define IN_CH 256
#define OUT_CH 64
#define N_EDGES 3200000

// ws layout (bytes)
#define WS_FLAG_OFF   0
#define WS_DEG_OFF    4096
#define WS_DINV_OFF   (4096 + 400000)
#define WS_H_OFF      (4096 + 800000)
// total needed: 4096 + 800000 + 25600000 = 26,404,096 bytes

// ---------------------------------------------------------------------------
// Probe: detect whether edge_index arrived as int64 (hi words all zero) or int32.
__global__ void probe_kernel(const unsigned* __restrict__ ei, int* __restrict__ flag) {
    if (blockIdx.x == 0 && threadIdx.x == 0) {
        int all0 = 1;
        for (int i = 0; i < 16; ++i) all0 &= (ei[2 * i + 1] == 0u);
        *flag = all0;  // 1 => int64 layout, 0 => int32 layout
    }
}

__device__ __forceinline__ int load_idx(const int* ei32, const long long* ei64,
                                        bool is64, long long pos) {
    return is64 ? (int)ei64[pos] : ei32[pos];
}

// ---------------------------------------------------------------------------
__global__ __launch_bounds__(256) void deg_kernel(const int* __restrict__ ei32,
                                                  const long long* __restrict__ ei64,
                                                  const int* __restrict__ flag,
                                                  unsigned* __restrict__ deg) {
    const bool is64 = (*flag != 0);
    int i = blockIdx.x * blockDim.x + threadIdx.x;
    const int stride = gridDim.x * blockDim.x;
    for (; i < N_EDGES; i += stride) {
        int d = load_idx(ei32, ei64, is64, (long long)N_EDGES + i);
        atomicAdd(&deg[d], 1u);
    }
}

__global__ __launch_bounds__(256) void dinv_kernel(const unsigned* __restrict__ deg,
                                                   float* __restrict__ dinv) {
    int i = blockIdx.x * blockDim.x + threadIdx.x;
    if (i < N_NODES) {
        // +1 for the self-loop
        dinv[i] = rsqrtf((float)(deg[i] + 1u));
    }
}

// ---------------------------------------------------------------------------
// h = x @ W   [N_NODES,256] @ [256,64] fp32
// 16 rows per block-iteration; W staged in 64x64 chunks (16KB); x rows staged
// (16 x 257 floats, padded to avoid bank conflicts). Each thread computes 4
// output channels for one row (cg = tid&15 -> channels 4cg..4cg+3, rl = tid>>4).
__global__ __launch_bounds__(256) void gemm_kernel(const float* __restrict__ x,
                                                   const float* __restrict__ W,
                                                   float* __restrict__ h) {
    __shared__ float xl[16][IN_CH + 1];   // 16*257*4 = 16448 B
    __shared__ float wl[64 * OUT_CH];     // 16 KB
    const int tid = threadIdx.x;
    const int cg = tid & 15;
    const int rl = tid >> 4;

    for (int g = blockIdx.x; g < N_NODES / 16; g += gridDim.x) {
        const int row0 = g * 16;
        __syncthreads();  // protect xl/wl from previous iteration's readers
        // stage x rows: 4096 floats = 1024 float4, 4 per thread
        #pragma unroll
        for (int i = 0; i < 4; ++i) {
            int f4 = tid + i * 256;          // 0..1023
            int r  = f4 >> 6;                // 64 float4 per row
            int kk = (f4 & 63) * 4;
            float4 v = *(const float4*)&x[(size_t)(row0 + r) * IN_CH + kk];
            xl[r][kk] = v.x; xl[r][kk + 1] = v.y; xl[r][kk + 2] = v.z; xl[r][kk + 3] = v.w;
        }
        float4 acc = {0.f, 0.f, 0.f, 0.f};
        for (int c4 = 0; c4 < IN_CH / 64; ++c4) {
            __syncthreads();
            // stage W chunk: rows c4*64..+63, all 64 cols = 4096 floats
            #pragma unroll
            for (int i = 0; i < 4; ++i) {
                int f4 = tid + i * 256;          // float4 index
                int kk = f4 >> 4;                // 16 float4 per W row
                int cc = (f4 & 15) * 4;
                *(float4*)&wl[kk * OUT_CH + cc] =
                    *(const float4*)&W[(size_t)(c4 * 64 + kk) * OUT_CH + cc];
            }
            __syncthreads();
            #pragma unroll 8
            for (int kk = 0; kk < 64; ++kk) {
                float xv = xl[rl][c4 * 64 + kk];
                float4 w4 = *(const float4*)&wl[kk * OUT_CH + cg * 4];
                acc.x = fmaf(xv, w4.x, acc.x);
                acc.y = fmaf(xv, w4.y, acc.y);
                acc.z = fmaf(xv, w4.z, acc.z);
                acc.w = fmaf(xv, w4.w, acc.w);
            }
        }
        *(float4*)&h[(size_t)(row0 + rl) * OUT_CH + cg * 4] = acc;
    }
}

// ---------------------------------------------------------------------------
// One wave per edge: lane c does out[dst*64+c] += h[src*64+c] * dinv[src]*dinv[dst]
__global__ __launch_bounds__(256) void scatter_kernel(const int* __restrict__ ei32,
                                                      const long long* __restrict__ ei64,
                                                      const int* __restrict__ flag,
                                                      const float* __restrict__ h,
                                                      const float* __restrict__ dinv,
                                                      float* __restrict__ out) {
    const bool is64 = (*flag != 0);
    const int lane = threadIdx.x & 63;
    int w = blockIdx.x * (blockDim.x >> 6) + (threadIdx.x >> 6);
    const int nw = gridDim.x * (blockDim.x >> 6);
    for (int e = w; e < N_EDGES; e += nw) {
        int s = load_idx(ei32, ei64, is64, e);
        int d = load_idx(ei32, ei64, is64, (long long)N_EDGES + e);
        float nrm = dinv[s] * dinv[d];
        float v = h[(size_t)s * OUT_CH + lane] * nrm;
        atomicAdd(&out[(size_t)d * OUT_CH + lane], v);
    }
}

// ---------------------------------------------------------------------------
// Epilogue: add self-loop + bias, relu, log_softmax over the 64 channels.
__global__ __launch_bounds__(256) void final_kernel(const float* __restrict__ h,
                                                    const float* __restrict__ dinv,
                                                    const float* __restrict__ b,
                                                    float* __restrict__ out) {
    const int lane = threadIdx.x & 63;
    int w = blockIdx.x * (blockDim.x >> 6) + (threadIdx.x >> 6);
    const int nw = gridDim.x * (blockDim.x >> 6);
    const float bias = b[lane];
    for (int n = w; n < N_NODES; n += nw) {
        float di = dinv[n];
        float v = out[(size_t)n * OUT_CH + lane]
                + h[(size_t)n * OUT_CH + lane] * di * di + bias;
        v = fmaxf(v, 0.f);
        float m = v;
        #pragma unroll
        for (int off = 32; off; off >>= 1) m = fmaxf(m, __shfl_xor(m, off));
        float ex = expf(v - m);
        float sum = ex;
        #pragma unroll
        for (int off = 32; off; off >>= 1) sum += __shfl_xor(sum, off);
        out[(size_t)n * OUT_CH + lane] = (v - m) - logf(sum);
    }
}

// ---------------------------------------------------------------------------
extern "C" void kernel_launch(void* const* d_in, const int* in_sizes, int n_in,
                              void* d_out, int out_size, void* d_ws, size_t ws_size,
                              hipStream_t stream) {
    const float* x  = (const float*)d_in[0];
    const void*  ei = d_in[1];
    const float* W  = (const float*)d_in[2];
    const float* b  = (const float*)d_in[3];
    float* out = (float*)d_out;

    char* ws = (char*)d_ws;
    int*      flag = (int*)(ws + WS_FLAG_OFF);
    unsigned* deg  = (unsigned*)(ws + WS_DEG_OFF);
    float*    dinv = (float*)(ws + WS_DINV_OFF);
    float*    h    = (float*)(ws + WS_H_OFF);

    const int* ei32      = (const int*)ei;
    const long long* ei64 = (const long long*)ei;

    // zero the accumulator (d_out) and degree counters every call
    hipMemsetAsync(d_out, 0, (size_t)out_size * sizeof(float), stream);
    hipMemsetAsync(deg, 0, (size_t)N_NODES * sizeof(unsigned), stream);

    probe_kernel<<<1, 64, 0, stream>>>((const unsigned*)ei, flag);
    deg_kernel<<<2048, 256, 0, stream>>>(ei32, ei64, flag, deg);
    dinv_kernel<<<(N_NODES + 255) / 256, 256, 0, stream>>>(deg, dinv);
    gemm_kernel<<<2048, 256, 0, stream>>>(x, W, h);
    scatter_kernel<<<2048, 256, 0, stream>>>(ei32, ei64, flag, h, dinv, out);
    final_kernel<<<1024, 256, 0, stream>>>(h, dinv, b, out);
}

// Round 2
// 654.412 us; speedup vs baseline: 1.4750x; 1.4750x over previous
//
#include <hip/hip_runtime.h>
#include <cstddef>
#include <cstdint>

#define N_NODES 100000
#define IN_CH 256
#define OUT_CH 64
#define N_EDGES 3200000

#define NBLK_SCAN ((N_NODES + 255) / 256)   // 391

// ---- CSR-path ws layout (bytes) ----
#define WS_FLAG_OFF   0
#define WS_DEG_OFF    4096
#define WS_DINV_OFF   (WS_DEG_OFF + 400000)
#define WS_OFF_OFF    (WS_DINV_OFF + 400000)
#define WS_PART_OFF   (WS_OFF_OFF + 400000)
#define WS_SSRC_OFF   (WS_PART_OFF + 4096)
#define WS_H_OFF      (WS_SSRC_OFF + 12800000)
#define WS_NEED_CSR   (WS_H_OFF + 25600000)          // 39,608,192 B

// ---- fallback (atomic) layout ----
#define WSF_H_OFF     (WS_DINV_OFF + 400000)          // 804,096
#define WS_NEED_FB    (WSF_H_OFF + 25600000)          // 26,404,096 B

// ---------------------------------------------------------------------------
// Probe: detect whether edge_index arrived as int64 (hi words all zero) or int32.
__global__ void probe_kernel(const unsigned* __restrict__ ei, int* __restrict__ flag) {
    if (blockIdx.x == 0 && threadIdx.x == 0) {
        int all0 = 1;
        for (int i = 0; i < 16; ++i) all0 &= (ei[2 * i + 1] == 0u);
        *flag = all0;  // 1 => int64 layout, 0 => int32 layout
    }
}

__device__ __forceinline__ int load_idx(const int* ei32, const long long* ei64,
                                        bool is64, long long pos) {
    return is64 ? (int)ei64[pos] : ei32[pos];
}

// ---------------------------------------------------------------------------
__global__ __launch_bounds__(256) void deg_kernel(const int* __restrict__ ei32,
                                                  const long long* __restrict__ ei64,
                                                  const int* __restrict__ flag,
                                                  unsigned* __restrict__ deg) {
    const bool is64 = (*flag != 0);
    int i = blockIdx.x * blockDim.x + threadIdx.x;
    const int stride = gridDim.x * blockDim.x;
    for (; i < N_EDGES; i += stride) {
        int d = load_idx(ei32, ei64, is64, (long long)N_EDGES + i);
        atomicAdd(&deg[d], 1u);
    }
}

__global__ __launch_bounds__(256) void dinv_kernel(const unsigned* __restrict__ deg,
                                                   float* __restrict__ dinv) {
    int i = blockIdx.x * blockDim.x + threadIdx.x;
    if (i < N_NODES) {
        dinv[i] = rsqrtf((float)(deg[i] + 1u));  // +1 for the self-loop
    }
}

// ---------------------------------------------------------------------------
// Exclusive scan of deg[0..N) into off[0..N): 3-kernel hierarchical scan.
__global__ __launch_bounds__(256) void scan1_kernel(const unsigned* __restrict__ deg,
                                                    unsigned* __restrict__ off,
                                                    unsigned* __restrict__ partial) {
    __shared__ unsigned s[256];
    const int t = threadIdx.x, b = blockIdx.x, i = b * 256 + t;
    unsigned v = (i < N_NODES) ? deg[i] : 0u;
    s[t] = v; __syncthreads();
    #pragma unroll
    for (int d = 1; d < 256; d <<= 1) {
        unsigned x = (t >= d) ? s[t - d] : 0u; __syncthreads();
        s[t] += x; __syncthreads();
    }
    if (i < N_NODES) off[i] = s[t];      // block-local INCLUSIVE scan
    if (t == 255) partial[b] = s[255];   // block total
}

__global__ __launch_bounds__(512) void scan2_kernel(unsigned* __restrict__ partial) {
    __shared__ unsigned s[512];
    const int t = threadIdx.x;
    unsigned v = (t < NBLK_SCAN) ? partial[t] : 0u;
    s[t] = v; __syncthreads();
    #pragma unroll
    for (int d = 1; d < 512; d <<= 1) {
        unsigned x = (t >= d) ? s[t - d] : 0u; __syncthreads();
        s[t] += x; __syncthreads();
    }
    if (t < NBLK_SCAN) partial[t] = s[t] - v;  // global EXCLUSIVE block offset
}

__global__ __launch_bounds__(256) void scan3_kernel(const unsigned* __restrict__ deg,
                                                    unsigned* __restrict__ off,
                                                    const unsigned* __restrict__ partial) {
    const int b = blockIdx.x, i = b * 256 + threadIdx.x;
    if (i < N_NODES) off[i] = off[i] - deg[i] + partial[b];  // global exclusive
}

// ---------------------------------------------------------------------------
// Bucket edges by dst: ssrc[pos] = src, segment cursors advance off[] in place.
// Post-condition: off[n] == segment END (original off[n] + deg[n]).
__global__ __launch_bounds__(256) void bucket_kernel(const int* __restrict__ ei32,
                                                     const long long* __restrict__ ei64,
                                                     const int* __restrict__ flag,
                                                     unsigned* __restrict__ off,
                                                     int* __restrict__ ssrc) {
    const bool is64 = (*flag != 0);
    int i = blockIdx.x * blockDim.x + threadIdx.x;
    const int stride = gridDim.x * blockDim.x;
    for (; i < N_EDGES; i += stride) {
        int s = load_idx(ei32, ei64, is64, i);
        int d = load_idx(ei32, ei64, is64, (long long)N_EDGES + i);
        unsigned p = atomicAdd(&off[d], 1u);
        ssrc[p] = s;
    }
}

// ---------------------------------------------------------------------------
// One wave per node: acc[lane] = (h[n][lane]*dinv[n] + sum_s h[s][lane]*dinv[s]) * dinv[n]
// then + bias, relu, log_softmax over 64 channels. Single coalesced write.
__global__ __launch_bounds__(256) void reduce_kernel(const float* __restrict__ h,
                                                     const float* __restrict__ dinv,
                                                     const unsigned* __restrict__ off,
                                                     const unsigned* __restrict__ deg,
                                                     const int* __restrict__ ssrc,
                                                     const float* __restrict__ b,
                                                     float* __restrict__ out) {
    const int n = blockIdx.x * 4 + (threadIdx.x >> 6);
    const int lane = threadIdx.x & 63;
    if (n >= N_NODES) return;
    const float dn = dinv[n];
    float acc = h[(size_t)n * OUT_CH + lane] * dn;   // self-loop (dinv[n] once; *dn later)
    const unsigned end = off[n];                      // post-bucket: inclusive end
    const unsigned cnt = deg[n];
    unsigned j = end - cnt;
    for (; j + 4 <= end; j += 4) {
        int s0 = ssrc[j], s1 = ssrc[j + 1], s2 = ssrc[j + 2], s3 = ssrc[j + 3];
        float f0 = dinv[s0], f1 = dinv[s1], f2 = dinv[s2], f3 = dinv[s3];
        float h0 = h[(size_t)s0 * OUT_CH + lane];
        float h1 = h[(size_t)s1 * OUT_CH + lane];
        float h2 = h[(size_t)s2 * OUT_CH + lane];
        float h3 = h[(size_t)s3 * OUT_CH + lane];
        acc = fmaf(h0, f0, acc);
        acc = fmaf(h1, f1, acc);
        acc = fmaf(h2, f2, acc);
        acc = fmaf(h3, f3, acc);
    }
    for (; j < end; ++j) {
        int s = ssrc[j];
        acc = fmaf(h[(size_t)s * OUT_CH + lane], dinv[s], acc);
    }
    float v = fmaf(acc, dn, b[lane]);
    v = fmaxf(v, 0.f);
    float m = v;
    #pragma unroll
    for (int o = 32; o; o >>= 1) m = fmaxf(m, __shfl_xor(m, o));
    float ex = expf(v - m);
    float sum = ex;
    #pragma unroll
    for (int o = 32; o; o >>= 1) sum += __shfl_xor(sum, o);
    out[(size_t)n * OUT_CH + lane] = (v - m) - logf(sum);
}

// ---------------------------------------------------------------------------
// h = x @ W   [N_NODES,256] @ [256,64] fp32 (vector ALU; no fp32 MFMA on CDNA4)
__global__ __launch_bounds__(256) void gemm_kernel(const float* __restrict__ x,
                                                   const float* __restrict__ W,
                                                   float* __restrict__ h) {
    __shared__ float xl[16][IN_CH + 1];
    __shared__ float wl[64 * OUT_CH];
    const int tid = threadIdx.x;
    const int cg = tid & 15;
    const int rl = tid >> 4;

    for (int g = blockIdx.x; g < N_NODES / 16; g += gridDim.x) {
        const int row0 = g * 16;
        __syncthreads();
        #pragma unroll
        for (int i = 0; i < 4; ++i) {
            int f4 = tid + i * 256;
            int r  = f4 >> 6;
            int kk = (f4 & 63) * 4;
            float4 v = *(const float4*)&x[(size_t)(row0 + r) * IN_CH + kk];
            xl[r][kk] = v.x; xl[r][kk + 1] = v.y; xl[r][kk + 2] = v.z; xl[r][kk + 3] = v.w;
        }
        float4 acc = {0.f, 0.f, 0.f, 0.f};
        for (int c4 = 0; c4 < IN_CH / 64; ++c4) {
            __syncthreads();
            #pragma unroll
            for (int i = 0; i < 4; ++i) {
                int f4 = tid + i * 256;
                int kk = f4 >> 4;
                int cc = (f4 & 15) * 4;
                *(float4*)&wl[kk * OUT_CH + cc] =
                    *(const float4*)&W[(size_t)(c4 * 64 + kk) * OUT_CH + cc];
            }
            __syncthreads();
            #pragma unroll 8
            for (int kk = 0; kk < 64; ++kk) {
                float xv = xl[rl][c4 * 64 + kk];
                float4 w4 = *(const float4*)&wl[kk * OUT_CH + cg * 4];
                acc.x = fmaf(xv, w4.x, acc.x);
                acc.y = fmaf(xv, w4.y, acc.y);
                acc.z = fmaf(xv, w4.z, acc.z);
                acc.w = fmaf(xv, w4.w, acc.w);
            }
        }
        *(float4*)&h[(size_t)(row0 + rl) * OUT_CH + cg * 4] = acc;
    }
}

// ---------------------------------------------------------------------------
// Fallback path (atomic scatter), used only if ws is too small for CSR path.
__global__ __launch_bounds__(256) void scatter_kernel(const int* __restrict__ ei32,
                                                      const long long* __restrict__ ei64,
                                                      const int* __restrict__ flag,
                                                      const float* __restrict__ h,
                                                      const float* __restrict__ dinv,
                                                      float* __restrict__ out) {
    const bool is64 = (*flag != 0);
    const int lane = threadIdx.x & 63;
    int w = blockIdx.x * (blockDim.x >> 6) + (threadIdx.x >> 6);
    const int nw = gridDim.x * (blockDim.x >> 6);
    for (int e = w; e < N_EDGES; e += nw) {
        int s = load_idx(ei32, ei64, is64, e);
        int d = load_idx(ei32, ei64, is64, (long long)N_EDGES + e);
        float nrm = dinv[s] * dinv[d];
        float v = h[(size_t)s * OUT_CH + lane] * nrm;
        atomicAdd(&out[(size_t)d * OUT_CH + lane], v);
    }
}

__global__ __launch_bounds__(256) void final_kernel(const float* __restrict__ h,
                                                    const float* __restrict__ dinv,
                                                    const float* __restrict__ b,
                                                    float* __restrict__ out) {
    const int lane = threadIdx.x & 63;
    int w = blockIdx.x * (blockDim.x >> 6) + (threadIdx.x >> 6);
    const int nw = gridDim.x * (blockDim.x >> 6);
    const float bias = b[lane];
    for (int n = w; n < N_NODES; n += nw) {
        float di = dinv[n];
        float v = out[(size_t)n * OUT_CH + lane]
                + h[(size_t)n * OUT_CH + lane] * di * di + bias;
        v = fmaxf(v, 0.f);
        float m = v;
        #pragma unroll
        for (int o = 32; o; o >>= 1) m = fmaxf(m, __shfl_xor(m, o));
        float ex = expf(v - m);
        float sum = ex;
        #pragma unroll
        for (int o = 32; o; o >>= 1) sum += __shfl_xor(sum, o);
        out[(size_t)n * OUT_CH + lane] = (v - m) - logf(sum);
    }
}

// ---------------------------------------------------------------------------
extern "C" void kernel_launch(void* const* d_in, const int* in_sizes, int n_in,
                              void* d_out, int out_size, void* d_ws, size_t ws_size,
                              hipStream_t stream) {
    const float* x  = (const float*)d_in[0];
    const void*  ei = d_in[1];
    const float* W  = (const float*)d_in[2];
    const float* b  = (const float*)d_in[3];
    float* out = (float*)d_out;

    char* ws = (char*)d_ws;
    int*      flag = (int*)(ws + WS_FLAG_OFF);
    unsigned* deg  = (unsigned*)(ws + WS_DEG_OFF);
    float*    dinv = (float*)(ws + WS_DINV_OFF);

    const int* ei32       = (const int*)ei;
    const long long* ei64 = (const long long*)ei;

    hipMemsetAsync(deg, 0, (size_t)N_NODES * sizeof(unsigned), stream);
    probe_kernel<<<1, 64, 0, stream>>>((const unsigned*)ei, flag);
    deg_kernel<<<2048, 256, 0, stream>>>(ei32, ei64, flag, deg);
    dinv_kernel<<<(N_NODES + 255) / 256, 256, 0, stream>>>(deg, dinv);

    if (ws_size >= (size_t)WS_NEED_CSR) {
        unsigned* off  = (unsigned*)(ws + WS_OFF_OFF);
        unsigned* part = (unsigned*)(ws + WS_PART_OFF);
        int*      ssrc = (int*)(ws + WS_SSRC_OFF);
        float*    h    = (float*)(ws + WS_H_OFF);

        scan1_kernel<<<NBLK_SCAN, 256, 0, stream>>>(deg, off, part);
        scan2_kernel<<<1, 512, 0, stream>>>(part);
        scan3_kernel<<<NBLK_SCAN, 256, 0, stream>>>(deg, off, part);
        gemm_kernel<<<2048, 256, 0, stream>>>(x, W, h);
        bucket_kernel<<<2048, 256, 0, stream>>>(ei32, ei64, flag, off, ssrc);
        reduce_kernel<<<(N_NODES + 3) / 4, 256, 0, stream>>>(h, dinv, off, deg, ssrc, b, out);
    } else {
        float* h = (float*)(ws + WSF_H_OFF);
        hipMemsetAsync(d_out, 0, (size_t)out_size * sizeof(float), stream);
        gemm_kernel<<<2048, 256, 0, stream>>>(x, W, h);
        scatter_kernel<<<2048, 256, 0, stream>>>(ei32, ei64, flag, h, dinv, out);
        final_kernel<<<1024, 256, 0, stream>>>(h, dinv, b, out);
    }
}